// Round 9
// baseline (141.126 us; speedup 1.0000x reference)
//
#include <hip/hip_runtime.h>
#include <hip/hip_bf16.h>

#define BB 2
#define SS 2048
#define HH 16
#define DD 64

#define LOG2E 1.4426950408889634f

typedef __bf16 bf16x8 __attribute__((ext_vector_type(8)));
typedef __bf16 bf16x4 __attribute__((ext_vector_type(4)));
typedef float f32x4 __attribute__((ext_vector_type(4)));

__device__ __forceinline__ void gld16(const __hip_bfloat16* g, __hip_bfloat16* l) {
    __builtin_amdgcn_global_load_lds(
        (const __attribute__((address_space(1))) unsigned int*)g,
        (__attribute__((address_space(3))) unsigned int*)l, 16, 0, 0);
}

// ---------------------------------------------------------------------------
// Kernel 1: fused Q/K/V projection + V transpose + Q pre-scaling.
//   Q, K  -> [B,H,S,D] bf16 (Q pre-multiplied by log2e/inv_scale)
//   V     -> Vt [B,H,D,S] bf16 (transposed)
// ---------------------------------------------------------------------------
__global__ __launch_bounds__(256) void proj_kernel(
    const float* __restrict__ xq, const float* __restrict__ xk,
    const float* __restrict__ xv,
    const float* __restrict__ Wq, const float* __restrict__ bq,
    const float* __restrict__ Wk, const float* __restrict__ bk,
    const float* __restrict__ Wv, const float* __restrict__ bv,
    const float* __restrict__ inv_scale_p,
    __hip_bfloat16* __restrict__ Qp, __hip_bfloat16* __restrict__ Kp,
    __hip_bfloat16* __restrict__ Vt)
{
    __shared__ float w_lds[64][65];                                  // [d][e]
    __shared__ __attribute__((aligned(16))) float x_lds[64][72];     // [row][d]
    __shared__ __attribute__((aligned(16))) __hip_bfloat16 vt_lds[64][72]; // [e][row]

    const int tid = threadIdx.x;
    const int bh = blockIdx.x;
    const int b = bh >> 4, h = bh & 15;
    const int s0 = blockIdx.y * 64;
    const int e = tid & 63;
    const int rg = tid >> 6;
    const float qscale = LOG2E / inv_scale_p[0];

    const float* xs[3] = {xq, xk, xv};
    const float* Ws[3] = {Wq, Wk, Wv};
    const float* Bs[3] = {bq, bk, bv};

#pragma unroll
    for (int m = 0; m < 3; ++m) {
        __syncthreads();
#pragma unroll
        for (int k = 0; k < 16; ++k) {
            const int i = tid + k * 256;
            w_lds[i & 63][i >> 6] = Ws[m][i];
        }
        {
            const int row = tid >> 2, f0 = tid & 3;
            const float* xrow = xs[m] + ((size_t)((b * SS + s0 + row) * HH + h)) * DD;
            float4* dst = (float4*)&x_lds[row][0];
            const float4* src = (const float4*)xrow;
#pragma unroll
            for (int j = 0; j < 4; ++j) dst[f0 + 4 * j] = src[f0 + 4 * j];
        }
        const float bias_e = Bs[m][e];
        __syncthreads();

        float acc[16];
#pragma unroll
        for (int it = 0; it < 16; ++it) acc[it] = bias_e;
#pragma unroll
        for (int dq = 0; dq < 16; ++dq) {
            const float w0 = w_lds[dq * 4 + 0][e];
            const float w1 = w_lds[dq * 4 + 1][e];
            const float w2 = w_lds[dq * 4 + 2][e];
            const float w3 = w_lds[dq * 4 + 3][e];
#pragma unroll
            for (int it = 0; it < 16; ++it) {
                const float4 x4 = *(const float4*)&x_lds[rg * 16 + it][dq * 4];
                acc[it] = fmaf(x4.x, w0, fmaf(x4.y, w1, fmaf(x4.z, w2, fmaf(x4.w, w3, acc[it]))));
            }
        }

        if (m == 0) {
#pragma unroll
            for (int it = 0; it < 16; ++it)
                Qp[((size_t)bh * SS + s0 + rg * 16 + it) * DD + e] =
                    __float2bfloat16(acc[it] * qscale);
        } else if (m == 1) {
#pragma unroll
            for (int it = 0; it < 16; ++it)
                Kp[((size_t)bh * SS + s0 + rg * 16 + it) * DD + e] =
                    __float2bfloat16(acc[it]);
        } else {
#pragma unroll
            for (int it = 0; it < 16; ++it)
                vt_lds[e][rg * 16 + it] = __float2bfloat16(acc[it]);
            __syncthreads();
            const int row2 = tid >> 2, f = tid & 3;
            bf16x8 vv0 = *(const bf16x8*)&vt_lds[row2][f * 16];
            bf16x8 vv1 = *(const bf16x8*)&vt_lds[row2][f * 16 + 8];
            __hip_bfloat16* dst = &Vt[((size_t)bh * DD + row2) * SS + s0 + f * 16];
            *(bf16x8*)dst = vv0;
            *(bf16x8*)(dst + 8) = vv1;
        }
    }
}

// ---------------------------------------------------------------------------
// Kernel 2: flash attention, 32 q-rows per wave (two 16-row groups sharing
// the same K/V fragments).  LDS-staged K/V (dbuf, XOR-swz), swapped QK^T
// with mask-as-C-init, defer-max softmax, l via ones-MFMA.
// grid = (B*H, S/128); block = 256 (4 waves); 1 barrier per t-tile.
// ---------------------------------------------------------------------------
__global__ __launch_bounds__(256, 2) void attn_kernel(
    const __hip_bfloat16* __restrict__ Qp, const __hip_bfloat16* __restrict__ Kp,
    const __hip_bfloat16* __restrict__ Vt, const float* __restrict__ mask,
    float* __restrict__ out)
{
    __shared__ __attribute__((aligned(16))) __hip_bfloat16 Kl[2][4096];
    __shared__ __attribute__((aligned(16))) __hip_bfloat16 Vl[2][4096];

    const int tid = threadIdx.x;
    const int lane = tid & 63;
    const int wave = tid >> 6;
    const int lm = lane & 15;
    const int lg = lane >> 4;
    const int bh = blockIdx.x;
    const int qt = blockIdx.y;
    const int b = bh >> 4;

    const __hip_bfloat16* Qb = Qp + (size_t)bh * SS * DD;
    const __hip_bfloat16* Kb = Kp + (size_t)bh * SS * DD;
    const __hip_bfloat16* Vtb = Vt + (size_t)bh * DD * SS;

    const int q0 = qt * 128 + wave * 32;    // wave owns q0..q0+31 (2 groups of 16)
    const float* mq[2];
    mq[0] = mask + (size_t)b * SS * SS + (size_t)(q0 + lm) * SS;
    mq[1] = mq[0] + 16 * SS;

    const int srow = lane >> 3;
    const int scol = ((lane & 7) ^ srow) * 8;
    const int swz = (lm & 7) << 4;

    bf16x8 qf[2][2];   // [group][kc]
#pragma unroll
    for (int g = 0; g < 2; ++g) {
        const __hip_bfloat16* qptr = Qb + (size_t)(q0 + g * 16 + lm) * DD + lg * 8;
        qf[g][0] = *reinterpret_cast<const bf16x8*>(qptr);
        qf[g][1] = *reinterpret_cast<const bf16x8*>(qptr + 32);
    }

    bf16x8 ones;
#pragma unroll
    for (int i = 0; i < 8; ++i) ones[i] = (__bf16)1.0f;

    f32x4 o[2][4];
    f32x4 lacc[2] = {f32x4{0.f, 0.f, 0.f, 0.f}, f32x4{0.f, 0.f, 0.f, 0.f}};
    float m_r[2] = {-1e30f, -1e30f};
#pragma unroll
    for (int g = 0; g < 2; ++g)
#pragma unroll
        for (int i = 0; i < 4; ++i) o[g][i] = f32x4{0.f, 0.f, 0.f, 0.f};

#define STAGE(bufi, t0s)                                                        \
    {                                                                           \
        _Pragma("unroll")                                                       \
        for (int cc = 0; cc < 2; ++cc) {                                        \
            const int c = wave * 2 + cc;                                        \
            const int row = c * 8 + srow;                                       \
            gld16(Kb + (size_t)((t0s) + row) * DD + scol, &Kl[bufi][c * 512]);  \
            gld16(Vtb + (size_t)row * SS + (t0s) + scol, &Vl[bufi][c * 512]);   \
        }                                                                       \
    }

#define KFRAG(nt, kc) (*(const bf16x8*)((const char*)Kl[buf] +                  \
        (((nt) * 16 + lm) << 7) + ((((kc) * 64) + lg * 16) ^ swz)))
#define VLO(dn, kc) (*(const bf16x4*)((const char*)Vl[buf] +                    \
        (((dn) * 16 + lm) << 7) + ((((kc) * 64) + lg * 8) ^ swz)))
#define VHI(dn, kc) (*(const bf16x4*)((const char*)Vl[buf] +                    \
        (((dn) * 16 + lm) << 7) + ((((kc) * 64 + 32) + lg * 8) ^ swz)))

    // prologue: stage tile 0
    STAGE(0, 0);
    __syncthreads();

    int buf = 0;
    for (int t0 = 0; t0 < SS; t0 += 64) {
        const bool has_next = (t0 + 64 < SS);
        if (has_next) STAGE(buf ^ 1, t0 + 64);

        // ---- mask loads -> MFMA C-init (log2 domain) ----
        f32x4 s[2][4];
#pragma unroll
        for (int g = 0; g < 2; ++g)
#pragma unroll
            for (int nt = 0; nt < 4; ++nt)
                s[g][nt] = (*(const f32x4*)&mq[g][t0 + nt * 16 + lg * 4]) * LOG2E;

        // ---- QK^T (swapped): K frags shared by both q-groups ----
#pragma unroll
        for (int kc = 0; kc < 2; ++kc) {
            bf16x8 k0 = KFRAG(0, kc), k1 = KFRAG(1, kc);
            bf16x8 k2 = KFRAG(2, kc), k3 = KFRAG(3, kc);
#pragma unroll
            for (int g = 0; g < 2; ++g) {
                s[g][0] = __builtin_amdgcn_mfma_f32_16x16x32_bf16(k0, qf[g][kc], s[g][0], 0, 0, 0);
                s[g][1] = __builtin_amdgcn_mfma_f32_16x16x32_bf16(k1, qf[g][kc], s[g][1], 0, 0, 0);
                s[g][2] = __builtin_amdgcn_mfma_f32_16x16x32_bf16(k2, qf[g][kc], s[g][2], 0, 0, 0);
                s[g][3] = __builtin_amdgcn_mfma_f32_16x16x32_bf16(k3, qf[g][kc], s[g][3], 0, 0, 0);
            }
        }

        // ---- V fragments (shared by both q-groups) ----
        bf16x8 vfr[8];
#pragma unroll
        for (int kc = 0; kc < 2; ++kc)
#pragma unroll
            for (int dn = 0; dn < 4; ++dn) {
                bf16x4 lo = VLO(dn, kc), hi = VHI(dn, kc);
                vfr[kc * 4 + dn] = __builtin_shufflevector(lo, hi, 0, 1, 2, 3, 4, 5, 6, 7);
            }

        // ---- defer-max per group + joint wave vote ----
        float pmax[2];
#pragma unroll
        for (int g = 0; g < 2; ++g) {
            float a0 = fmaxf(s[g][0][0], fmaxf(s[g][0][1], s[g][0][2]));
            float a1 = fmaxf(s[g][0][3], fmaxf(s[g][1][0], s[g][1][1]));
            float a2 = fmaxf(s[g][1][2], fmaxf(s[g][1][3], s[g][2][0]));
            float a3 = fmaxf(s[g][2][1], fmaxf(s[g][2][2], s[g][2][3]));
            float a4 = fmaxf(s[g][3][0], fmaxf(s[g][3][1], s[g][3][2]));
            float p = fmaxf(s[g][3][3], fmaxf(a0, a1));
            pmax[g] = fmaxf(p, fmaxf(a2, fmaxf(a3, a4)));
        }

        if (!__all((pmax[0] - m_r[0] <= 11.5f) && (pmax[1] - m_r[1] <= 11.5f))) {
            // slow path (rare): full row-max reduce + rescale both groups
#pragma unroll
            for (int g = 0; g < 2; ++g) {
                float mx = pmax[g];
                mx = fmaxf(mx, __shfl_xor(mx, 16));
                mx = fmaxf(mx, __shfl_xor(mx, 32));
                const float mn = fmaxf(m_r[g], mx);
                const float alpha = exp2f(m_r[g] - mn);
                m_r[g] = mn;
#pragma unroll
                for (int r = 0; r < 4; ++r) {
                    const float a = __shfl(alpha, lg * 4 + r);
                    o[g][0][r] *= a; o[g][1][r] *= a;
                    o[g][2][r] *= a; o[g][3][r] *= a;
                    lacc[g][r] *= a;
                }
            }
        }

        // ---- P = exp2(s - m); pack; PV + l for both groups ----
#pragma unroll
        for (int g = 0; g < 2; ++g) {
#pragma unroll
            for (int nt = 0; nt < 4; ++nt)
#pragma unroll
                for (int r = 0; r < 4; ++r)
                    s[g][nt][r] = __builtin_amdgcn_exp2f(s[g][nt][r] - m_r[g]);

            bf16x8 pfa[2];
#pragma unroll
            for (int kc = 0; kc < 2; ++kc) {
                union { bf16x8 v; __hip_bfloat162 h[4]; } u;
                u.h[0] = __float22bfloat162_rn(make_float2(s[g][2 * kc][0], s[g][2 * kc][1]));
                u.h[1] = __float22bfloat162_rn(make_float2(s[g][2 * kc][2], s[g][2 * kc][3]));
                u.h[2] = __float22bfloat162_rn(make_float2(s[g][2 * kc + 1][0], s[g][2 * kc + 1][1]));
                u.h[3] = __float22bfloat162_rn(make_float2(s[g][2 * kc + 1][2], s[g][2 * kc + 1][3]));
                pfa[kc] = u.v;
            }

#pragma unroll
            for (int kc = 0; kc < 2; ++kc) {
                lacc[g] = __builtin_amdgcn_mfma_f32_16x16x32_bf16(pfa[kc], ones, lacc[g], 0, 0, 0);
#pragma unroll
                for (int dn = 0; dn < 4; ++dn)
                    o[g][dn] = __builtin_amdgcn_mfma_f32_16x16x32_bf16(pfa[kc], vfr[kc * 4 + dn], o[g][dn], 0, 0, 0);
            }
        }

        __syncthreads();
        buf ^= 1;
    }

    // ---- epilogue: normalize and store both groups ----
#pragma unroll
    for (int g = 0; g < 2; ++g)
#pragma unroll
        for (int r = 0; r < 4; ++r) {
            const float inv_l = 1.0f / lacc[g][r];
            const int q = q0 + g * 16 + lg * 4 + r;
#pragma unroll
            for (int dn = 0; dn < 4; ++dn)
                out[((size_t)bh * SS + q) * DD + dn * 16 + lm] = o[g][dn][r] * inv_l;
        }
#undef STAGE
#undef KFRAG
#undef VLO
#undef VHI
}

extern "C" void kernel_launch(void* const* d_in, const int* in_sizes, int n_in,
                              void* d_out, int out_size, void* d_ws, size_t ws_size,
                              hipStream_t stream) {
    const float* xq        = (const float*)d_in[0];
    const float* xk        = (const float*)d_in[1];
    const float* xv        = (const float*)d_in[2];
    const float* mask      = (const float*)d_in[3];
    const float* inv_scale = (const float*)d_in[4];
    const float* Wq        = (const float*)d_in[5];
    const float* bq        = (const float*)d_in[6];
    const float* Wk        = (const float*)d_in[7];
    const float* bk        = (const float*)d_in[8];
    const float* Wv        = (const float*)d_in[9];
    const float* bv        = (const float*)d_in[10];

    __hip_bfloat16* Qp = (__hip_bfloat16*)d_ws;
    __hip_bfloat16* Kp = Qp + (size_t)BB * HH * SS * DD;
    __hip_bfloat16* Vt = Kp + (size_t)BB * HH * SS * DD;
    float* out = (float*)d_out;

    proj_kernel<<<dim3(BB * HH, SS / 64), dim3(256), 0, stream>>>(
        xq, xk, xv, Wq, bq, Wk, bk, Wv, bv, inv_scale, Qp, Kp, Vt);

    attn_kernel<<<dim3(BB * HH, SS / 128), dim3(256), 0, stream>>>(
        Qp, Kp, Vt, mask, out);
}

// Round 10
// 132.263 us; speedup vs baseline: 1.0670x; 1.0670x over previous
//
#include <hip/hip_runtime.h>
#include <hip/hip_bf16.h>

#define BB 2
#define SS 2048
#define HH 16
#define DD 64

#define LOG2E 1.4426950408889634f

typedef __bf16 bf16x8 __attribute__((ext_vector_type(8)));
typedef __bf16 bf16x4 __attribute__((ext_vector_type(4)));
typedef float f32x4 __attribute__((ext_vector_type(4)));

__device__ __forceinline__ void gld16(const __hip_bfloat16* g, __hip_bfloat16* l) {
    __builtin_amdgcn_global_load_lds(
        (const __attribute__((address_space(1))) unsigned int*)g,
        (__attribute__((address_space(3))) unsigned int*)l, 16, 0, 0);
}

// ---------------------------------------------------------------------------
// Kernel 1: fused Q/K/V projection + V transpose + Q pre-scaling.
//   Q, K  -> [B,H,S,D] bf16 (Q pre-multiplied by log2e/inv_scale)
//   V     -> Vt [B,H,D,S] bf16 (transposed)
// ---------------------------------------------------------------------------
__global__ __launch_bounds__(256) void proj_kernel(
    const float* __restrict__ xq, const float* __restrict__ xk,
    const float* __restrict__ xv,
    const float* __restrict__ Wq, const float* __restrict__ bq,
    const float* __restrict__ Wk, const float* __restrict__ bk,
    const float* __restrict__ Wv, const float* __restrict__ bv,
    const float* __restrict__ inv_scale_p,
    __hip_bfloat16* __restrict__ Qp, __hip_bfloat16* __restrict__ Kp,
    __hip_bfloat16* __restrict__ Vt)
{
    __shared__ float w_lds[64][65];                                  // [d][e]
    __shared__ __attribute__((aligned(16))) float x_lds[64][72];     // [row][d]
    __shared__ __attribute__((aligned(16))) __hip_bfloat16 vt_lds[64][72]; // [e][row]

    const int tid = threadIdx.x;
    const int bh = blockIdx.x;
    const int b = bh >> 4, h = bh & 15;
    const int s0 = blockIdx.y * 64;
    const int e = tid & 63;
    const int rg = tid >> 6;
    const float qscale = LOG2E / inv_scale_p[0];

    const float* xs[3] = {xq, xk, xv};
    const float* Ws[3] = {Wq, Wk, Wv};
    const float* Bs[3] = {bq, bk, bv};

#pragma unroll
    for (int m = 0; m < 3; ++m) {
        __syncthreads();
#pragma unroll
        for (int k = 0; k < 16; ++k) {
            const int i = tid + k * 256;
            w_lds[i & 63][i >> 6] = Ws[m][i];
        }
        {
            const int row = tid >> 2, f0 = tid & 3;
            const float* xrow = xs[m] + ((size_t)((b * SS + s0 + row) * HH + h)) * DD;
            float4* dst = (float4*)&x_lds[row][0];
            const float4* src = (const float4*)xrow;
#pragma unroll
            for (int j = 0; j < 4; ++j) dst[f0 + 4 * j] = src[f0 + 4 * j];
        }
        const float bias_e = Bs[m][e];
        __syncthreads();

        float acc[16];
#pragma unroll
        for (int it = 0; it < 16; ++it) acc[it] = bias_e;
#pragma unroll
        for (int dq = 0; dq < 16; ++dq) {
            const float w0 = w_lds[dq * 4 + 0][e];
            const float w1 = w_lds[dq * 4 + 1][e];
            const float w2 = w_lds[dq * 4 + 2][e];
            const float w3 = w_lds[dq * 4 + 3][e];
#pragma unroll
            for (int it = 0; it < 16; ++it) {
                const float4 x4 = *(const float4*)&x_lds[rg * 16 + it][dq * 4];
                acc[it] = fmaf(x4.x, w0, fmaf(x4.y, w1, fmaf(x4.z, w2, fmaf(x4.w, w3, acc[it]))));
            }
        }

        if (m == 0) {
#pragma unroll
            for (int it = 0; it < 16; ++it)
                Qp[((size_t)bh * SS + s0 + rg * 16 + it) * DD + e] =
                    __float2bfloat16(acc[it] * qscale);
        } else if (m == 1) {
#pragma unroll
            for (int it = 0; it < 16; ++it)
                Kp[((size_t)bh * SS + s0 + rg * 16 + it) * DD + e] =
                    __float2bfloat16(acc[it]);
        } else {
#pragma unroll
            for (int it = 0; it < 16; ++it)
                vt_lds[e][rg * 16 + it] = __float2bfloat16(acc[it]);
            __syncthreads();
            const int row2 = tid >> 2, f = tid & 3;
            bf16x8 vv0 = *(const bf16x8*)&vt_lds[row2][f * 16];
            bf16x8 vv1 = *(const bf16x8*)&vt_lds[row2][f * 16 + 8];
            __hip_bfloat16* dst = &Vt[((size_t)bh * DD + row2) * SS + s0 + f * 16];
            *(bf16x8*)dst = vv0;
            *(bf16x8*)(dst + 8) = vv1;
        }
    }
}

// ---------------------------------------------------------------------------
// Kernel 2: flash attention.  LDS-staged K/V (dbuf, XOR-swz), swapped QK^T
// with mask-as-C-init, defer-max softmax, l via ones-MFMA, setprio around
// MFMA clusters.  XCD-aware block remap: the 16 h-blocks sharing a mask row
// get hw ids == same value (mod 8) -> same XCD -> mask L2-resident.
// grid = 1024 linear; block = 256 (4 waves); 1 barrier per t-tile.
// ---------------------------------------------------------------------------
__global__ __launch_bounds__(256, 4) void attn_kernel(
    const __hip_bfloat16* __restrict__ Qp, const __hip_bfloat16* __restrict__ Kp,
    const __hip_bfloat16* __restrict__ Vt, const float* __restrict__ mask,
    float* __restrict__ out)
{
    __shared__ __attribute__((aligned(16))) __hip_bfloat16 Kl[2][4096];
    __shared__ __attribute__((aligned(16))) __hip_bfloat16 Vl[2][4096];

    const int tid = threadIdx.x;
    const int lane = tid & 63;
    const int wave = tid >> 6;
    const int lm = lane & 15;
    const int lg = lane >> 4;

    // ---- XCD-aware bijective remap of the 1024-block linear id ----
    // hw = (g%8) + 8*h + 128*(g/8), g = qt*2+b  ==> all h for fixed (b,qt)
    // share hw%8 (same XCD under round-robin dispatch).
    const int hw = blockIdx.x;
    const int x = hw & 127;
    const int h = x >> 3;                 // head 0..15
    const int g = ((hw >> 7) << 3) + (x & 7);
    const int qt = g >> 1;
    const int b = g & 1;
    const int bh = b * 16 + h;

    const __hip_bfloat16* Qb = Qp + (size_t)bh * SS * DD;
    const __hip_bfloat16* Kb = Kp + (size_t)bh * SS * DD;
    const __hip_bfloat16* Vtb = Vt + (size_t)bh * DD * SS;

    const int q0 = qt * 64 + wave * 16;
    const float* mq = mask + (size_t)b * SS * SS + (size_t)(q0 + lm) * SS;

    const int srow = lane >> 3;
    const int scol = ((lane & 7) ^ srow) * 8;
    const int swz = (lm & 7) << 4;

    bf16x8 qf[2];
    {
        const __hip_bfloat16* qptr = Qb + (size_t)(q0 + lm) * DD + lg * 8;
        qf[0] = *reinterpret_cast<const bf16x8*>(qptr);
        qf[1] = *reinterpret_cast<const bf16x8*>(qptr + 32);
    }

    bf16x8 ones;
#pragma unroll
    for (int i = 0; i < 8; ++i) ones[i] = (__bf16)1.0f;

    f32x4 o[4];
    f32x4 lacc = f32x4{0.f, 0.f, 0.f, 0.f};
    float m_r = -1e30f;
#pragma unroll
    for (int i = 0; i < 4; ++i) o[i] = f32x4{0.f, 0.f, 0.f, 0.f};

#define STAGE(bufi, t0s)                                                        \
    {                                                                           \
        _Pragma("unroll")                                                       \
        for (int cc = 0; cc < 2; ++cc) {                                        \
            const int c = wave * 2 + cc;                                        \
            const int row = c * 8 + srow;                                       \
            gld16(Kb + (size_t)((t0s) + row) * DD + scol, &Kl[bufi][c * 512]);  \
            gld16(Vtb + (size_t)row * SS + (t0s) + scol, &Vl[bufi][c * 512]);   \
        }                                                                       \
    }

#define KFRAG(nt, kc) (*(const bf16x8*)((const char*)Kl[buf] +                  \
        (((nt) * 16 + lm) << 7) + ((((kc) * 64) + lg * 16) ^ swz)))
#define VLO(dn, kc) (*(const bf16x4*)((const char*)Vl[buf] +                    \
        (((dn) * 16 + lm) << 7) + ((((kc) * 64) + lg * 8) ^ swz)))
#define VHI(dn, kc) (*(const bf16x4*)((const char*)Vl[buf] +                    \
        (((dn) * 16 + lm) << 7) + ((((kc) * 64 + 32) + lg * 8) ^ swz)))

    // prologue: stage tile 0
    STAGE(0, 0);
    __syncthreads();

    int buf = 0;
    for (int t0 = 0; t0 < SS; t0 += 64) {
        const bool has_next = (t0 + 64 < SS);

        // ---- mask load first (C-init dependency; L2-resident via remap) ----
        f32x4 mv[4];
#pragma unroll
        for (int nt = 0; nt < 4; ++nt)
            mv[nt] = *(const f32x4*)&mq[t0 + nt * 16 + lg * 4];

        if (has_next) STAGE(buf ^ 1, t0 + 64);

        // ---- QK^T (swapped) with C-init = mask*log2e.  col=q(lm), row=t ----
        f32x4 s[4];
#pragma unroll
        for (int nt = 0; nt < 4; ++nt) s[nt] = mv[nt] * LOG2E;
        __builtin_amdgcn_s_setprio(1);
#pragma unroll
        for (int kc = 0; kc < 2; ++kc) {
            bf16x8 k0 = KFRAG(0, kc), k1 = KFRAG(1, kc);
            bf16x8 k2 = KFRAG(2, kc), k3 = KFRAG(3, kc);
            s[0] = __builtin_amdgcn_mfma_f32_16x16x32_bf16(k0, qf[kc], s[0], 0, 0, 0);
            s[1] = __builtin_amdgcn_mfma_f32_16x16x32_bf16(k1, qf[kc], s[1], 0, 0, 0);
            s[2] = __builtin_amdgcn_mfma_f32_16x16x32_bf16(k2, qf[kc], s[2], 0, 0, 0);
            s[3] = __builtin_amdgcn_mfma_f32_16x16x32_bf16(k3, qf[kc], s[3], 0, 0, 0);
        }
        __builtin_amdgcn_s_setprio(0);

        // ---- V fragments: DS reads + clean concat (shufflevector) ----
        bf16x8 vfr[8];
#pragma unroll
        for (int kc = 0; kc < 2; ++kc)
#pragma unroll
            for (int dn = 0; dn < 4; ++dn) {
                bf16x4 lo = VLO(dn, kc), hi = VHI(dn, kc);
                vfr[kc * 4 + dn] = __builtin_shufflevector(lo, hi, 0, 1, 2, 3, 4, 5, 6, 7);
            }

        // ---- defer-max: lane-local max via max3-fusable tree + wave vote ----
        float a0 = fmaxf(s[0][0], fmaxf(s[0][1], s[0][2]));
        float a1 = fmaxf(s[0][3], fmaxf(s[1][0], s[1][1]));
        float a2 = fmaxf(s[1][2], fmaxf(s[1][3], s[2][0]));
        float a3 = fmaxf(s[2][1], fmaxf(s[2][2], s[2][3]));
        float a4 = fmaxf(s[3][0], fmaxf(s[3][1], s[3][2]));
        float pmax = fmaxf(s[3][3], fmaxf(a0, a1));
        pmax = fmaxf(pmax, fmaxf(a2, fmaxf(a3, a4)));

        if (!__all(pmax - m_r <= 11.5f)) {
            // slow path (rare): full row-max reduce + rescale state
            float mx = pmax;
            mx = fmaxf(mx, __shfl_xor(mx, 16));
            mx = fmaxf(mx, __shfl_xor(mx, 32));
            const float mn = fmaxf(m_r, mx);
            const float alpha = exp2f(m_r - mn);
            m_r = mn;
#pragma unroll
            for (int r = 0; r < 4; ++r) {
                const float a = __shfl(alpha, lg * 4 + r);
                o[0][r] *= a; o[1][r] *= a; o[2][r] *= a; o[3][r] *= a;
                lacc[r] *= a;
            }
        }

        // ---- P = exp2(s - m) (raw v_exp_f32; defer-max bounds the arg) ----
#pragma unroll
        for (int nt = 0; nt < 4; ++nt)
#pragma unroll
            for (int r = 0; r < 4; ++r)
                s[nt][r] = __builtin_amdgcn_exp2f(s[nt][r] - m_r);

        // ---- pack P via packed bf16 cvt + union assembly ----
        bf16x8 pfa[2];
#pragma unroll
        for (int kc = 0; kc < 2; ++kc) {
            union { bf16x8 v; __hip_bfloat162 h[4]; } u;
            u.h[0] = __float22bfloat162_rn(make_float2(s[2 * kc][0], s[2 * kc][1]));
            u.h[1] = __float22bfloat162_rn(make_float2(s[2 * kc][2], s[2 * kc][3]));
            u.h[2] = __float22bfloat162_rn(make_float2(s[2 * kc + 1][0], s[2 * kc + 1][1]));
            u.h[3] = __float22bfloat162_rn(make_float2(s[2 * kc + 1][2], s[2 * kc + 1][3]));
            pfa[kc] = u.v;
        }

        // ---- O += P @ V ; l += P @ ones ----
        __builtin_amdgcn_s_setprio(1);
#pragma unroll
        for (int kc = 0; kc < 2; ++kc) {
            lacc = __builtin_amdgcn_mfma_f32_16x16x32_bf16(pfa[kc], ones, lacc, 0, 0, 0);
#pragma unroll
            for (int dn = 0; dn < 4; ++dn)
                o[dn] = __builtin_amdgcn_mfma_f32_16x16x32_bf16(pfa[kc], vfr[kc * 4 + dn], o[dn], 0, 0, 0);
        }
        __builtin_amdgcn_s_setprio(0);

        __syncthreads();
        buf ^= 1;
    }

    // ---- epilogue: normalize (l already in o-row layout) and store ----
#pragma unroll
    for (int r = 0; r < 4; ++r) {
        const float inv_l = 1.0f / lacc[r];
        const int q = q0 + lg * 4 + r;
#pragma unroll
        for (int dn = 0; dn < 4; ++dn)
            out[((size_t)bh * SS + q) * DD + dn * 16 + lm] = o[dn][r] * inv_l;
    }
#undef STAGE
#undef KFRAG
#undef VLO
#undef VHI
}

extern "C" void kernel_launch(void* const* d_in, const int* in_sizes, int n_in,
                              void* d_out, int out_size, void* d_ws, size_t ws_size,
                              hipStream_t stream) {
    const float* xq        = (const float*)d_in[0];
    const float* xk        = (const float*)d_in[1];
    const float* xv        = (const float*)d_in[2];
    const float* mask      = (const float*)d_in[3];
    const float* inv_scale = (const float*)d_in[4];
    const float* Wq        = (const float*)d_in[5];
    const float* bq        = (const float*)d_in[6];
    const float* Wk        = (const float*)d_in[7];
    const float* bk        = (const float*)d_in[8];
    const float* Wv        = (const float*)d_in[9];
    const float* bv        = (const float*)d_in[10];

    __hip_bfloat16* Qp = (__hip_bfloat16*)d_ws;
    __hip_bfloat16* Kp = Qp + (size_t)BB * HH * SS * DD;
    __hip_bfloat16* Vt = Kp + (size_t)BB * HH * SS * DD;
    float* out = (float*)d_out;

    proj_kernel<<<dim3(BB * HH, SS / 64), dim3(256), 0, stream>>>(
        xq, xk, xv, Wq, bq, Wk, bk, Wv, bv, inv_scale, Qp, Kp, Vt);

    attn_kernel<<<dim3(1024), dim3(256), 0, stream>>>(
        Qp, Kp, Vt, mask, out);
}

// Round 11
// 124.146 us; speedup vs baseline: 1.1368x; 1.0654x over previous
//
#include <hip/hip_runtime.h>
#include <hip/hip_bf16.h>

#define BB 2
#define SS 2048
#define HH 16
#define DD 64

#define LOG2E 1.4426950408889634f

typedef __bf16 bf16x8 __attribute__((ext_vector_type(8)));
typedef float f32x4 __attribute__((ext_vector_type(4)));
typedef float f32x16 __attribute__((ext_vector_type(16)));

__device__ __forceinline__ void gld16(const __hip_bfloat16* g, __hip_bfloat16* l) {
    __builtin_amdgcn_global_load_lds(
        (const __attribute__((address_space(1))) unsigned int*)g,
        (__attribute__((address_space(3))) unsigned int*)l, 16, 0, 0);
}

// ---------------------------------------------------------------------------
// Kernel 1: fused Q/K/V projection + V transpose + Q pre-scaling. (unchanged)
// ---------------------------------------------------------------------------
__global__ __launch_bounds__(256) void proj_kernel(
    const float* __restrict__ xq, const float* __restrict__ xk,
    const float* __restrict__ xv,
    const float* __restrict__ Wq, const float* __restrict__ bq,
    const float* __restrict__ Wk, const float* __restrict__ bk,
    const float* __restrict__ Wv, const float* __restrict__ bv,
    const float* __restrict__ inv_scale_p,
    __hip_bfloat16* __restrict__ Qp, __hip_bfloat16* __restrict__ Kp,
    __hip_bfloat16* __restrict__ Vt)
{
    __shared__ float w_lds[64][65];
    __shared__ __attribute__((aligned(16))) float x_lds[64][72];
    __shared__ __attribute__((aligned(16))) __hip_bfloat16 vt_lds[64][72];

    const int tid = threadIdx.x;
    const int bh = blockIdx.x;
    const int b = bh >> 4, h = bh & 15;
    const int s0 = blockIdx.y * 64;
    const int e = tid & 63;
    const int rg = tid >> 6;
    const float qscale = LOG2E / inv_scale_p[0];

    const float* xs[3] = {xq, xk, xv};
    const float* Ws[3] = {Wq, Wk, Wv};
    const float* Bs[3] = {bq, bk, bv};

#pragma unroll
    for (int m = 0; m < 3; ++m) {
        __syncthreads();
#pragma unroll
        for (int k = 0; k < 16; ++k) {
            const int i = tid + k * 256;
            w_lds[i & 63][i >> 6] = Ws[m][i];
        }
        {
            const int row = tid >> 2, f0 = tid & 3;
            const float* xrow = xs[m] + ((size_t)((b * SS + s0 + row) * HH + h)) * DD;
            float4* dst = (float4*)&x_lds[row][0];
            const float4* src = (const float4*)xrow;
#pragma unroll
            for (int j = 0; j < 4; ++j) dst[f0 + 4 * j] = src[f0 + 4 * j];
        }
        const float bias_e = Bs[m][e];
        __syncthreads();

        float acc[16];
#pragma unroll
        for (int it = 0; it < 16; ++it) acc[it] = bias_e;
#pragma unroll
        for (int dq = 0; dq < 16; ++dq) {
            const float w0 = w_lds[dq * 4 + 0][e];
            const float w1 = w_lds[dq * 4 + 1][e];
            const float w2 = w_lds[dq * 4 + 2][e];
            const float w3 = w_lds[dq * 4 + 3][e];
#pragma unroll
            for (int it = 0; it < 16; ++it) {
                const float4 x4 = *(const float4*)&x_lds[rg * 16 + it][dq * 4];
                acc[it] = fmaf(x4.x, w0, fmaf(x4.y, w1, fmaf(x4.z, w2, fmaf(x4.w, w3, acc[it]))));
            }
        }

        if (m == 0) {
#pragma unroll
            for (int it = 0; it < 16; ++it)
                Qp[((size_t)bh * SS + s0 + rg * 16 + it) * DD + e] =
                    __float2bfloat16(acc[it] * qscale);
        } else if (m == 1) {
#pragma unroll
            for (int it = 0; it < 16; ++it)
                Kp[((size_t)bh * SS + s0 + rg * 16 + it) * DD + e] =
                    __float2bfloat16(acc[it]);
        } else {
#pragma unroll
            for (int it = 0; it < 16; ++it)
                vt_lds[e][rg * 16 + it] = __float2bfloat16(acc[it]);
            __syncthreads();
            const int row2 = tid >> 2, f = tid & 3;
            bf16x8 vv0 = *(const bf16x8*)&vt_lds[row2][f * 16];
            bf16x8 vv1 = *(const bf16x8*)&vt_lds[row2][f * 16 + 8];
            __hip_bfloat16* dst = &Vt[((size_t)bh * DD + row2) * SS + s0 + f * 16];
            *(bf16x8*)dst = vv0;
            *(bf16x8*)(dst + 8) = vv1;
        }
    }
}

// ---------------------------------------------------------------------------
// Kernel 2: flash attention, 32x32x16 MFMA, 32 q-rows/wave, QBLK=128.
// LDS-staged K/V (dbuf, XOR-swz, conflict-free b128), swapped QK^T with
// mask-as-C-init, defer-max softmax (lane-local), in-register P->A refrag
// via one shfl_xor(32) per pair, l via ones-MFMA.
// grid = 512 remapped (2 blocks/CU); block = 256 (4 waves); 1 barrier/tile.
// ---------------------------------------------------------------------------
__global__ __launch_bounds__(256, 2) void attn_kernel(
    const __hip_bfloat16* __restrict__ Qp, const __hip_bfloat16* __restrict__ Kp,
    const __hip_bfloat16* __restrict__ Vt, const float* __restrict__ mask,
    float* __restrict__ out)
{
    __shared__ __attribute__((aligned(16))) __hip_bfloat16 Kl[2][4096];
    __shared__ __attribute__((aligned(16))) __hip_bfloat16 Vl[2][4096];

    const int tid = threadIdx.x;
    const int lane = tid & 63;
    const int wave = tid >> 6;
    const int ln31 = lane & 31;
    const int hi = lane >> 5;

    // XCD-aware bijective remap (512 blocks): hw = (g%8) + 8h + 128(g/8),
    // g = qt*2+b -> all heads of one (b,qt) share hw%8 (same XCD: mask in L2).
    const int hw = blockIdx.x;
    const int x = hw & 127;
    const int h = x >> 3;
    const int g = ((hw >> 7) << 3) + (x & 7);
    const int qt = g >> 1;
    const int b = g & 1;
    const int bh = b * 16 + h;

    const __hip_bfloat16* Qb = Qp + (size_t)bh * SS * DD;
    const __hip_bfloat16* Kb = Kp + (size_t)bh * SS * DD;
    const __hip_bfloat16* Vtb = Vt + (size_t)bh * DD * SS;

    const int q0 = qt * 128 + wave * 32;          // wave owns q0..q0+31
    const float* mq = mask + (size_t)b * SS * SS + (size_t)(q0 + ln31) * SS;

    const int srow = lane >> 3;
    const int scol = ((lane & 7) ^ srow) * 8;     // pre-swizzled staging source
    const int rswz = (lane & 7) << 4;             // read-side XOR (row&7 == lane&7)

    // Q fragments: B-operand, col=q=ln31, k-chunk kc: elems kc*16 + hi*8 + i
    bf16x8 qf[4];
    {
        const __hip_bfloat16* qptr = Qb + (size_t)(q0 + ln31) * DD + hi * 8;
#pragma unroll
        for (int kc = 0; kc < 4; ++kc)
            qf[kc] = *reinterpret_cast<const bf16x8*>(qptr + kc * 16);
    }

    bf16x8 ones;
#pragma unroll
    for (int i = 0; i < 8; ++i) ones[i] = (__bf16)1.0f;

    f32x16 o[2];          // C: col=d(ln31), row=q=(r&3)+8(r>>2)+4hi
    f32x16 lacc;
    float m_r = -1e30f;   // running max (log2 domain) for q = q0+ln31
#pragma unroll
    for (int r = 0; r < 16; ++r) { o[0][r] = 0.f; o[1][r] = 0.f; lacc[r] = 0.f; }

#define STAGE(bufi, t0s)                                                        \
    {                                                                           \
        _Pragma("unroll")                                                       \
        for (int cc = 0; cc < 2; ++cc) {                                        \
            const int c = wave * 2 + cc;                                        \
            const int row = c * 8 + srow;                                       \
            gld16(Kb + (size_t)((t0s) + row) * DD + scol, &Kl[bufi][c * 512]);  \
            gld16(Vtb + (size_t)row * SS + (t0s) + scol, &Vl[bufi][c * 512]);   \
        }                                                                       \
    }

    // row = nt*32 + ln31 (K) / dblk*32 + ln31 (V); col = kc*32 + hi*16, XOR rswz
#define KFRAG(nt, kc) (*(const bf16x8*)((const char*)Kl[buf] +                  \
        (nt) * 4096 + ln31 * 128 + (((kc) * 32 + hi * 16) ^ rswz)))
#define VFRAG(dblk, kc) (*(const bf16x8*)((const char*)Vl[buf] +                \
        (dblk) * 4096 + ln31 * 128 + (((kc) * 32 + hi * 16) ^ rswz)))

    STAGE(0, 0);
    __syncthreads();

    int buf = 0;
    for (int t0 = 0; t0 < SS; t0 += 64) {
        const bool has_next = (t0 + 64 < SS);

        // ---- mask loads (C-init values) ----
        f32x4 mv[2][4];
#pragma unroll
        for (int nt = 0; nt < 2; ++nt)
#pragma unroll
            for (int gi = 0; gi < 4; ++gi)
                mv[nt][gi] = *(const f32x4*)&mq[t0 + nt * 32 + hi * 4 + gi * 8];

        if (has_next) STAGE(buf ^ 1, t0 + 64);

        // ---- QK^T (swapped): C col=q(ln31), row=t=nt*32+(r&3)+8(r>>2)+4hi ----
        f32x16 s[2];
#pragma unroll
        for (int nt = 0; nt < 2; ++nt)
#pragma unroll
            for (int r = 0; r < 16; ++r)
                s[nt][r] = mv[nt][r >> 2][r & 3] * LOG2E;

        __builtin_amdgcn_s_setprio(1);
#pragma unroll
        for (int kc = 0; kc < 4; ++kc) {
            bf16x8 k0 = KFRAG(0, kc);
            bf16x8 k1 = KFRAG(1, kc);
            s[0] = __builtin_amdgcn_mfma_f32_32x32x16_bf16(k0, qf[kc], s[0], 0, 0, 0);
            s[1] = __builtin_amdgcn_mfma_f32_32x32x16_bf16(k1, qf[kc], s[1], 0, 0, 0);
        }
        __builtin_amdgcn_s_setprio(0);

        // ---- V fragments: issue DS reads now, hide under softmax ----
        bf16x8 vfr[2][4];
#pragma unroll
        for (int dblk = 0; dblk < 2; ++dblk)
#pragma unroll
            for (int kc = 0; kc < 4; ++kc)
                vfr[dblk][kc] = VFRAG(dblk, kc);

        // ---- defer-max: lane-local max over 32 vals + wave vote ----
        float pmax = fmaxf(s[0][0], fmaxf(s[0][1], s[0][2]));
#pragma unroll
        for (int r = 3; r < 16; r += 3)
            pmax = fmaxf(pmax, fmaxf(s[0][r], fmaxf(s[0][(r + 1) & 15], s[0][(r + 2) & 15])));
#pragma unroll
        for (int r = 0; r < 16; r += 4)
            pmax = fmaxf(pmax, fmaxf(fmaxf(s[1][r], s[1][r + 1]), fmaxf(s[1][r + 2], s[1][r + 3])));

        if (!__all(pmax - m_r <= 11.5f)) {
            // slow path (rare): full row-max (half-exchange) + rescale state
            float mx = fmaxf(pmax, __shfl_xor(pmax, 32));
            const float mn = fmaxf(m_r, mx);
            const float alpha = exp2f(m_r - mn);
            m_r = mn;
#pragma unroll
            for (int r = 0; r < 16; ++r) {
                const float a = __shfl(alpha, (r & 3) + 8 * (r >> 2) + 4 * hi);
                o[0][r] *= a; o[1][r] *= a; lacc[r] *= a;
            }
        }

        // ---- P = exp2(s - m) in place ----
#pragma unroll
        for (int nt = 0; nt < 2; ++nt)
#pragma unroll
            for (int r = 0; r < 16; ++r)
                s[nt][r] = __builtin_amdgcn_exp2f(s[nt][r] - m_r);

        // ---- P -> PV A-fragments, fully in-register.
        // Lane holds P[q=ln31][t = nt*32 + (r&3)+8(r>>2)+4hi].  A-frag for
        // chunk kc needs t = kc*16 + hi*8 + i.  Missing t-quads live in the
        // peer half-lane (same q) -> one shfl_xor(32) per pack pair.
        bf16x8 pfa[4];
#pragma unroll
        for (int nt = 0; nt < 2; ++nt) {
            unsigned c[8];
#pragma unroll
            for (int j = 0; j < 8; ++j) {
                union { __hip_bfloat162 hh; unsigned u; } cu;
                cu.hh = __float22bfloat162_rn(make_float2(s[nt][2 * j], s[nt][2 * j + 1]));
                c[j] = cu.u;
            }
#pragma unroll
            for (int half = 0; half < 2; ++half) {
                const unsigned c0 = c[half * 4 + 0], c1 = c[half * 4 + 1];
                const unsigned c2 = c[half * 4 + 2], c3 = c[half * 4 + 3];
                const unsigned X  = hi ? c0 : c2;
                const unsigned Y  = (unsigned)__shfl_xor((int)X, 32);
                const unsigned X2 = hi ? c1 : c3;
                const unsigned Y2 = (unsigned)__shfl_xor((int)X2, 32);
                union { bf16x8 v; unsigned w[4]; } pu;
                pu.w[0] = hi ? Y : c0;
                pu.w[1] = hi ? Y2 : c1;
                pu.w[2] = hi ? c2 : Y;
                pu.w[3] = hi ? c3 : Y2;
                pfa[nt * 2 + half] = pu.v;
            }
        }

        // ---- O += P @ V ; l += P @ ones.  C: col=d(ln31), row=q ----
        __builtin_amdgcn_s_setprio(1);
#pragma unroll
        for (int kc = 0; kc < 4; ++kc) {
            lacc = __builtin_amdgcn_mfma_f32_32x32x16_bf16(pfa[kc], ones, lacc, 0, 0, 0);
            o[0] = __builtin_amdgcn_mfma_f32_32x32x16_bf16(pfa[kc], vfr[0][kc], o[0], 0, 0, 0);
            o[1] = __builtin_amdgcn_mfma_f32_32x32x16_bf16(pfa[kc], vfr[1][kc], o[1], 0, 0, 0);
        }
        __builtin_amdgcn_s_setprio(0);

        __syncthreads();
        buf ^= 1;
    }

    // ---- epilogue: normalize and store [B,H,S,D] f32 (coalesced over d) ----
#pragma unroll
    for (int r = 0; r < 16; ++r) {
        const float inv_l = 1.0f / lacc[r];
        const int q = q0 + (r & 3) + 8 * (r >> 2) + 4 * hi;
        float* orow = out + ((size_t)bh * SS + q) * DD + ln31;
        orow[0]  = o[0][r] * inv_l;
        orow[32] = o[1][r] * inv_l;
    }
#undef STAGE
#undef KFRAG
#undef VFRAG
}

extern "C" void kernel_launch(void* const* d_in, const int* in_sizes, int n_in,
                              void* d_out, int out_size, void* d_ws, size_t ws_size,
                              hipStream_t stream) {
    const float* xq        = (const float*)d_in[0];
    const float* xk        = (const float*)d_in[1];
    const float* xv        = (const float*)d_in[2];
    const float* mask      = (const float*)d_in[3];
    const float* inv_scale = (const float*)d_in[4];
    const float* Wq        = (const float*)d_in[5];
    const float* bq        = (const float*)d_in[6];
    const float* Wk        = (const float*)d_in[7];
    const float* bk        = (const float*)d_in[8];
    const float* Wv        = (const float*)d_in[9];
    const float* bv        = (const float*)d_in[10];

    __hip_bfloat16* Qp = (__hip_bfloat16*)d_ws;
    __hip_bfloat16* Kp = Qp + (size_t)BB * HH * SS * DD;
    __hip_bfloat16* Vt = Kp + (size_t)BB * HH * SS * DD;
    float* out = (float*)d_out;

    proj_kernel<<<dim3(BB * HH, SS / 64), dim3(256), 0, stream>>>(
        xq, xk, xv, Wq, bq, Wk, bk, Wv, bv, inv_scale, Qp, Kp, Vt);

    attn_kernel<<<dim3(512), dim3(256), 0, stream>>>(
        Qp, Kp, Vt, mask, out);
}